// Round 1
// baseline (406.858 us; speedup 1.0000x reference)
//
#include <hip/hip_runtime.h>
#include <hip/hip_bf16.h>
#include <stdint.h>

typedef unsigned short u16;
typedef __bf16 bf16x8 __attribute__((ext_vector_type(8)));
typedef float f32x4 __attribute__((ext_vector_type(4)));

#define K_DIM 2048
#define M_DIM 8192   // B*S = 4*2048 tokens
#define N_DIM 8192   // D_OUT
#define QBF   127.0f
#define EPSF  1e-5f

// RNE float->bf16 (exact for our small integers)
__device__ __forceinline__ u16 f2bf(float f) {
    union { float f; unsigned u; } v; v.f = f;
    unsigned r = v.u + 0x7FFFu + ((v.u >> 16) & 1u);
    return (u16)(r >> 16);
}

__device__ __forceinline__ void load_lds16(const void* gsrc, void* ldst) {
    __builtin_amdgcn_global_load_lds(
        (__attribute__((address_space(1))) void*)gsrc,
        (__attribute__((address_space(3))) void*)ldst,
        16, 0, 0);
}

// ---------- Kernel 1: deterministic partial |W| sums ----------
__global__ __launch_bounds__(256) void k_abs_partial(const float* __restrict__ w,
                                                     float* __restrict__ partial) {
    __shared__ float red[256];
    int t = threadIdx.x, b = blockIdx.x;
    const float4* w4 = (const float4*)w;
    size_t base = (size_t)b * 2048;  // 2048 float4 per block
    float s = 0.f;
#pragma unroll
    for (int j = 0; j < 8; ++j) {
        float4 v = w4[base + j * 256 + t];
        s += fabsf(v.x) + fabsf(v.y) + fabsf(v.z) + fabsf(v.w);
    }
    red[t] = s; __syncthreads();
    for (int off = 128; off > 0; off >>= 1) {
        if (t < off) red[t] += red[t + off];
        __syncthreads();
    }
    if (t == 0) partial[b] = red[0];
}

// ---------- Kernel 2: gamma = sum(partial)/count ----------
__global__ __launch_bounds__(256) void k_gamma(const float* __restrict__ partial,
                                               float* __restrict__ gamma) {
    __shared__ float red[256];
    int t = threadIdx.x;
    float s = 0.f;
#pragma unroll
    for (int j = 0; j < 8; ++j) s += partial[t + j * 256];
    red[t] = s; __syncthreads();
    for (int off = 128; off > 0; off >>= 1) {
        if (t < off) red[t] += red[t + off];
        __syncthreads();
    }
    if (t == 0) gamma[0] = red[0] / 16777216.0f;
}

// ---------- Kernel 3: ternary-quantize W -> bf16 ----------
__global__ __launch_bounds__(256) void k_quant_w(const float* __restrict__ w,
                                                 const float* __restrict__ gamma,
                                                 u16* __restrict__ wq) {
    float g = fmaxf(gamma[0], EPSF);
    int tid = blockIdx.x * 256 + threadIdx.x;   // 1,048,576 threads
    const float4* w4 = (const float4*)w;
    ushort4* q4 = (ushort4*)wq;
#pragma unroll
    for (int i = 0; i < 4; ++i) {
        int idx = tid + i * 1048576;
        float4 v = w4[idx];
        ushort4 o;
        o.x = f2bf(fminf(fmaxf(rintf(v.x / g), -1.f), 1.f));
        o.y = f2bf(fminf(fmaxf(rintf(v.y / g), -1.f), 1.f));
        o.z = f2bf(fminf(fmaxf(rintf(v.z / g), -1.f), 1.f));
        o.w = f2bf(fminf(fmaxf(rintf(v.w / g), -1.f), 1.f));
        q4[idx] = o;
    }
}

// ---------- Kernel 4: per-token absmax-quantize x -> bf16 ints, alpha ----------
__global__ __launch_bounds__(256) void k_quant_x(const float* __restrict__ x,
                                                 u16* __restrict__ xq,
                                                 float* __restrict__ alpha) {
    __shared__ float red[256];
    int t = threadIdx.x, row = blockIdx.x;
    const float4* x4 = (const float4*)x + (size_t)row * 512;
    float4 v0 = x4[t], v1 = x4[t + 256];
    float m = fmaxf(fmaxf(fabsf(v0.x), fabsf(v0.y)), fmaxf(fabsf(v0.z), fabsf(v0.w)));
    m = fmaxf(m, fmaxf(fmaxf(fabsf(v1.x), fabsf(v1.y)), fmaxf(fabsf(v1.z), fabsf(v1.w))));
    red[t] = m; __syncthreads();
    for (int off = 128; off > 0; off >>= 1) {
        if (t < off) red[t] = fmaxf(red[t], red[t + off]);
        __syncthreads();
    }
    float a = red[0];
    if (t == 0) alpha[row] = a;
    float den = fmaxf(a, EPSF);
    ushort4* q4 = (ushort4*)xq + (size_t)row * 512;
    ushort4 o0, o1;
    o0.x = f2bf(fminf(fmaxf(rintf(v0.x * QBF / den), -QBF), QBF));
    o0.y = f2bf(fminf(fmaxf(rintf(v0.y * QBF / den), -QBF), QBF));
    o0.z = f2bf(fminf(fmaxf(rintf(v0.z * QBF / den), -QBF), QBF));
    o0.w = f2bf(fminf(fmaxf(rintf(v0.w * QBF / den), -QBF), QBF));
    o1.x = f2bf(fminf(fmaxf(rintf(v1.x * QBF / den), -QBF), QBF));
    o1.y = f2bf(fminf(fmaxf(rintf(v1.y * QBF / den), -QBF), QBF));
    o1.z = f2bf(fminf(fmaxf(rintf(v1.z * QBF / den), -QBF), QBF));
    o1.w = f2bf(fminf(fmaxf(rintf(v1.w * QBF / den), -QBF), QBF));
    q4[t] = o0; q4[t + 256] = o1;
}

// ---------- Kernel 5: bf16 MFMA GEMM, 128x128 tile, BK=64 (m97 structure) ----------
// A = xq [M,K] row-major, B = wq [N,K] row-major (B^T form). out[m,n] += sum_k A[m,k]*B[n,k]
// LDS: As 128x64 bf16 (16KB) + Bs 128x64 bf16 (16KB). Rows are 128B -> XOR-swizzle
// 16B chunks: phys_chunk = logical_chunk ^ (row&7). global_load_lds writes linearly,
// so the SOURCE address is pre-swizzled; ds_read applies the same XOR.
__global__ __launch_bounds__(256, 2) void k_gemm(const u16* __restrict__ xq,
                                                 const u16* __restrict__ wq,
                                                 const float* __restrict__ alpha,
                                                 const float* __restrict__ gamma,
                                                 float* __restrict__ out) {
    __shared__ __align__(16) char smem[32768];  // [0,16384)=As, [16384,32768)=Bs

    int bid = blockIdx.x;
    int wg = (bid & 7) * 512 + (bid >> 3);      // XCD-bijective swizzle (4096 % 8 == 0)
    int tm = wg >> 6, tn = wg & 63;

    int t = threadIdx.x;
    int w = t >> 6, l = t & 63;

    // ---- staging descriptors: 8 x 1KB issues per wave (32KB total per block) ----
    const u16* srcb[8];
    int dstb[8];
#pragma unroll
    for (int j = 0; j < 8; ++j) {
        int ob = (w * 8 + j) * 1024 + l * 16;   // combined linear byte offset
        int isB = ob >> 14;                      // 0 -> As, 1 -> Bs
        int o = ob & 16383;
        int r = o >> 7;                          // tile row 0..127
        int c = (o >> 4) & 7;                    // phys 16B chunk 0..7
        int sc = c ^ (r & 7);                    // pre-swizzled source chunk
        const u16* base = isB ? wq : xq;
        int grow = (isB ? tn : tm) * 128 + r;
        srcb[j] = base + (size_t)grow * K_DIM + sc * 8;
        dstb[j] = (w * 8 + j) * 1024;            // wave-uniform LDS base
    }

    f32x4 acc[4][4];
#pragma unroll
    for (int m = 0; m < 4; ++m)
#pragma unroll
        for (int n = 0; n < 4; ++n) acc[m][n] = (f32x4){0.f, 0.f, 0.f, 0.f};

    int wr = w >> 1, wc = w & 1;                 // 2x2 waves, each owns 64x64
    int lrow = l & 15, kgrp = l >> 4, swz = l & 7;
    int aoff[4], boff[4];
#pragma unroll
    for (int i = 0; i < 4; ++i) {
        aoff[i] = (wr * 64 + i * 16 + lrow) * 128;          // byte offset in As
        boff[i] = 16384 + (wc * 64 + i * 16 + lrow) * 128;  // byte offset in Bs
    }
    // physical chunk byte offset for kk=0,1 (logical chunk = kk*4 + kgrp, row&7 == l&7)
    int pc[2] = { ((kgrp) ^ swz) * 16, ((4 + kgrp) ^ swz) * 16 };

    for (int k0 = 0; k0 < K_DIM; k0 += 64) {
#pragma unroll
        for (int j = 0; j < 8; ++j)
            load_lds16(srcb[j] + k0, smem + dstb[j]);
        __syncthreads();
#pragma unroll
        for (int kk = 0; kk < 2; ++kk) {
            bf16x8 a[4], b[4];
#pragma unroll
            for (int i = 0; i < 4; ++i) {
                a[i] = *(const bf16x8*)(smem + aoff[i] + pc[kk]);
                b[i] = *(const bf16x8*)(smem + boff[i] + pc[kk]);
            }
#pragma unroll
            for (int m = 0; m < 4; ++m)
#pragma unroll
                for (int n = 0; n < 4; ++n)
                    acc[m][n] = __builtin_amdgcn_mfma_f32_16x16x32_bf16(
                        a[m], b[n], acc[m][n], 0, 0, 0);
        }
        __syncthreads();
    }

    // ---- epilogue: out = acc * alpha[row] * gamma / 127 ----
    float gam = gamma[0];
    int orow0 = tm * 128 + wr * 64;
    int ocol0 = tn * 128 + wc * 64 + lrow;
    float sc4[4][4];
#pragma unroll
    for (int m = 0; m < 4; ++m)
#pragma unroll
        for (int r = 0; r < 4; ++r)
            sc4[m][r] = alpha[orow0 + m * 16 + kgrp * 4 + r] * gam / QBF;
#pragma unroll
    for (int m = 0; m < 4; ++m)
#pragma unroll
        for (int n = 0; n < 4; ++n)
#pragma unroll
            for (int r = 0; r < 4; ++r) {
                int row = orow0 + m * 16 + kgrp * 4 + r;
                out[(size_t)row * N_DIM + ocol0 + n * 16] = acc[m][n][r] * sc4[m][r];
            }
}

extern "C" void kernel_launch(void* const* d_in, const int* in_sizes, int n_in,
                              void* d_out, int out_size, void* d_ws, size_t ws_size,
                              hipStream_t stream) {
    const float* x  = (const float*)d_in[0];   // [4,2048,2048]
    const float* wt = (const float*)d_in[1];   // [8192,2048]
    float* out = (float*)d_out;                // [4,2048,8192] fp32

    char* ws = (char*)d_ws;
    u16*   xq      = (u16*)ws;                          // 33,554,432 B
    u16*   wq      = (u16*)(ws + 33554432);             // 33,554,432 B
    float* alpha   = (float*)(ws + 67108864);           // 32,768 B
    float* partial = (float*)(ws + 67141632);           // 8,192 B
    float* gamma   = (float*)(ws + 67149824);           // 4 B

    k_abs_partial<<<2048, 256, 0, stream>>>(wt, partial);
    k_gamma<<<1, 256, 0, stream>>>(partial, gamma);
    k_quant_w<<<4096, 256, 0, stream>>>(wt, gamma, wq);
    k_quant_x<<<8192, 256, 0, stream>>>(x, xq, alpha);
    k_gemm<<<4096, 256, 0, stream>>>(xq, wq, alpha, gamma, out);
}

// Round 2
// 341.158 us; speedup vs baseline: 1.1926x; 1.1926x over previous
//
#include <hip/hip_runtime.h>
#include <hip/hip_bf16.h>
#include <stdint.h>

typedef unsigned short u16;
typedef __bf16 bf16x8 __attribute__((ext_vector_type(8)));
typedef float f32x4 __attribute__((ext_vector_type(4)));

#define K_DIM 2048
#define M_DIM 8192   // B*S = 4*2048 tokens
#define N_DIM 8192   // D_OUT
#define QBF   127.0f
#define EPSF  1e-5f
#define NT    64     // K_DIM / 32 sub-tiles

// RNE float->bf16 (exact for our small integers)
__device__ __forceinline__ u16 f2bf(float f) {
    union { float f; unsigned u; } v; v.f = f;
    unsigned r = v.u + 0x7FFFu + ((v.u >> 16) & 1u);
    return (u16)(r >> 16);
}

__device__ __forceinline__ void load_lds16(const void* gsrc, void* ldst) {
    __builtin_amdgcn_global_load_lds(
        (__attribute__((address_space(1))) void*)gsrc,
        (__attribute__((address_space(3))) void*)ldst,
        16, 0, 0);
}

// ---------- Kernel 1: deterministic partial |W| sums ----------
__global__ __launch_bounds__(256) void k_abs_partial(const float* __restrict__ w,
                                                     float* __restrict__ partial) {
    __shared__ float red[256];
    int t = threadIdx.x, b = blockIdx.x;
    const float4* w4 = (const float4*)w;
    size_t base = (size_t)b * 2048;
    float s = 0.f;
#pragma unroll
    for (int j = 0; j < 8; ++j) {
        float4 v = w4[base + j * 256 + t];
        s += fabsf(v.x) + fabsf(v.y) + fabsf(v.z) + fabsf(v.w);
    }
    red[t] = s; __syncthreads();
    for (int off = 128; off > 0; off >>= 1) {
        if (t < off) red[t] += red[t + off];
        __syncthreads();
    }
    if (t == 0) partial[b] = red[0];
}

// ---------- Kernel 2: gamma = sum(partial)/count ----------
__global__ __launch_bounds__(256) void k_gamma(const float* __restrict__ partial,
                                               float* __restrict__ gamma) {
    __shared__ float red[256];
    int t = threadIdx.x;
    float s = 0.f;
#pragma unroll
    for (int j = 0; j < 8; ++j) s += partial[t + j * 256];
    red[t] = s; __syncthreads();
    for (int off = 128; off > 0; off >>= 1) {
        if (t < off) red[t] += red[t + off];
        __syncthreads();
    }
    if (t == 0) gamma[0] = red[0] / 16777216.0f;
}

// ---------- Kernel 3: ternary-quantize W -> bf16 ----------
__global__ __launch_bounds__(256) void k_quant_w(const float* __restrict__ w,
                                                 const float* __restrict__ gamma,
                                                 u16* __restrict__ wq) {
    float g = fmaxf(gamma[0], EPSF);
    int tid = blockIdx.x * 256 + threadIdx.x;
    const float4* w4 = (const float4*)w;
    ushort4* q4 = (ushort4*)wq;
#pragma unroll
    for (int i = 0; i < 4; ++i) {
        int idx = tid + i * 1048576;
        float4 v = w4[idx];
        ushort4 o;
        o.x = f2bf(fminf(fmaxf(rintf(v.x / g), -1.f), 1.f));
        o.y = f2bf(fminf(fmaxf(rintf(v.y / g), -1.f), 1.f));
        o.z = f2bf(fminf(fmaxf(rintf(v.z / g), -1.f), 1.f));
        o.w = f2bf(fminf(fmaxf(rintf(v.w / g), -1.f), 1.f));
        q4[idx] = o;
    }
}

// ---------- Kernel 4: per-token absmax-quantize x -> bf16 ints, alpha ----------
__global__ __launch_bounds__(256) void k_quant_x(const float* __restrict__ x,
                                                 u16* __restrict__ xq,
                                                 float* __restrict__ alpha) {
    __shared__ float red[256];
    int t = threadIdx.x, row = blockIdx.x;
    const float4* x4 = (const float4*)x + (size_t)row * 512;
    float4 v0 = x4[t], v1 = x4[t + 256];
    float m = fmaxf(fmaxf(fabsf(v0.x), fabsf(v0.y)), fmaxf(fabsf(v0.z), fabsf(v0.w)));
    m = fmaxf(m, fmaxf(fmaxf(fabsf(v1.x), fabsf(v1.y)), fmaxf(fabsf(v1.z), fabsf(v1.w))));
    red[t] = m; __syncthreads();
    for (int off = 128; off > 0; off >>= 1) {
        if (t < off) red[t] = fmaxf(red[t], red[t + off]);
        __syncthreads();
    }
    float a = red[0];
    if (t == 0) alpha[row] = a;
    float den = fmaxf(a, EPSF);
    ushort4* q4 = (ushort4*)xq + (size_t)row * 512;
    ushort4 o0, o1;
    o0.x = f2bf(fminf(fmaxf(rintf(v0.x * QBF / den), -QBF), QBF));
    o0.y = f2bf(fminf(fmaxf(rintf(v0.y * QBF / den), -QBF), QBF));
    o0.z = f2bf(fminf(fmaxf(rintf(v0.z * QBF / den), -QBF), QBF));
    o0.w = f2bf(fminf(fmaxf(rintf(v0.w * QBF / den), -QBF), QBF));
    o1.x = f2bf(fminf(fmaxf(rintf(v1.x * QBF / den), -QBF), QBF));
    o1.y = f2bf(fminf(fmaxf(rintf(v1.y * QBF / den), -QBF), QBF));
    o1.z = f2bf(fminf(fmaxf(rintf(v1.z * QBF / den), -QBF), QBF));
    o1.w = f2bf(fminf(fmaxf(rintf(v1.w * QBF / den), -QBF), QBF));
    q4[t] = o0; q4[t + 256] = o1;
}

// ---------- Kernel 5: 256x256 deep-pipelined bf16 MFMA GEMM ----------
// A = xq [M,K], B = wq [N,K] row-major. 512 threads = 8 waves (2x4), wave owns 128x64.
// BK=32 sub-tiles, 4-deep LDS ring (4 x 32KB). Per sub-tile: A 256x32 bf16 (16KB,
// 64B rows of 4 x 16B chunks, phys_chunk = log_chunk ^ (row&3)) then B same at +16KB.
// Prefetch 3 sub-tiles ahead -> per-tile wait is vmcnt(8), never 0 (T4).
// Per-wave vmcnt ledger: 4 global_load_lds per tile; at tile top outstanding = 12
// (tiles kt..kt+2), need oldest 4 -> vmcnt(8); tail: NT-2 -> 4, NT-1 -> 0.
__global__ __launch_bounds__(512, 2) void k_gemm(const u16* __restrict__ xq,
                                                 const u16* __restrict__ wq,
                                                 const float* __restrict__ alpha,
                                                 const float* __restrict__ gamma,
                                                 float* __restrict__ out) {
    __shared__ __align__(16) char smem[131072];  // 4 ring buffers x 32KB

    int bid = blockIdx.x;
    int wg = (bid & 7) * 128 + (bid >> 3);       // XCD-bijective (1024 % 8 == 0)
    int tm = wg >> 5, tn = wg & 31;

    int t = threadIdx.x;
    int w = t >> 6, l = t & 63;
    int wr = w >> 2, wc = w & 3;                 // 2x4 waves

    // ---- staging descriptors: 4 regions/wave/tile, 1KB each (waves 0-3: A, 4-7: B)
    const u16* srcb[4];
    int dstq[4];
    {
        int rsub = l >> 2;                       // row within 16-row region
        int clog = (l & 3) ^ (rsub & 3);         // pre-swizzled source chunk
#pragma unroll
        for (int j = 0; j < 4; ++j) {
            int q = w * 4 + j;                   // region 0..31
            int isB = q >> 4;
            int r = (q & 15) * 16 + rsub;        // tile-local row 0..255
            int grow = (isB ? tn : tm) * 256 + r;
            srcb[j] = (isB ? wq : xq) + (size_t)grow * K_DIM + clog * 8;
            dstq[j] = q * 1024;                  // wave-uniform LDS offset
        }
    }

    f32x4 acc[8][4];
#pragma unroll
    for (int m = 0; m < 8; ++m)
#pragma unroll
        for (int n = 0; n < 4; ++n) acc[m][n] = (f32x4){0.f, 0.f, 0.f, 0.f};

    int lrow = l & 15, kgrp = l >> 4;
    int cph = (kgrp ^ (lrow & 3)) * 16;          // swizzled read chunk
    int aoff = (wr * 128 + lrow) * 64 + cph;     // + mf*1024
    int boff = 16384 + (wc * 64 + lrow) * 64 + cph;  // + nf*1024

    // ---- prologue: stage sub-tiles 0..2 (12 issues/wave outstanding)
#pragma unroll
    for (int p = 0; p < 3; ++p)
#pragma unroll
        for (int j = 0; j < 4; ++j)
            load_lds16(srcb[j] + (size_t)p * 32, smem + p * 32768 + dstq[j]);

    for (int kt = 0; kt < NT; ++kt) {
        char* sb = smem + (kt & 3) * 32768;
        // tile-boundary wait: retire sub-tile kt's 4 loads, keep the rest in flight
        if (kt < NT - 2)       asm volatile("s_waitcnt vmcnt(8)" ::: "memory");
        else if (kt == NT - 2) asm volatile("s_waitcnt vmcnt(4)" ::: "memory");
        else                   asm volatile("s_waitcnt vmcnt(0)" ::: "memory");
        __builtin_amdgcn_s_barrier();

        bf16x8 b[4];
        {   // ---- phase 0: mf 0-3 ----
            bf16x8 a[4];
#pragma unroll
            for (int i = 0; i < 4; ++i) {
                a[i] = *(const bf16x8*)(sb + aoff + i * 1024);
                b[i] = *(const bf16x8*)(sb + boff + i * 1024);
            }
            if (kt + 3 < NT) {
                char* db = smem + ((kt + 3) & 3) * 32768;
                load_lds16(srcb[0] + (size_t)(kt + 3) * 32, db + dstq[0]);
                load_lds16(srcb[1] + (size_t)(kt + 3) * 32, db + dstq[1]);
            }
            __builtin_amdgcn_s_barrier();
            asm volatile("s_waitcnt lgkmcnt(0)" ::: "memory");
            __builtin_amdgcn_sched_barrier(0);
            __builtin_amdgcn_s_setprio(1);
#pragma unroll
            for (int m = 0; m < 4; ++m)
#pragma unroll
                for (int n = 0; n < 4; ++n)
                    acc[m][n] = __builtin_amdgcn_mfma_f32_16x16x32_bf16(
                        a[m], b[n], acc[m][n], 0, 0, 0);
            __builtin_amdgcn_s_setprio(0);
            __builtin_amdgcn_s_barrier();
        }
        {   // ---- phase 1: mf 4-7 (reuse b) ----
            bf16x8 a[4];
#pragma unroll
            for (int i = 0; i < 4; ++i)
                a[i] = *(const bf16x8*)(sb + aoff + (i + 4) * 1024);
            if (kt + 3 < NT) {
                char* db = smem + ((kt + 3) & 3) * 32768;
                load_lds16(srcb[2] + (size_t)(kt + 3) * 32, db + dstq[2]);
                load_lds16(srcb[3] + (size_t)(kt + 3) * 32, db + dstq[3]);
            }
            __builtin_amdgcn_s_barrier();
            asm volatile("s_waitcnt lgkmcnt(0)" ::: "memory");
            __builtin_amdgcn_sched_barrier(0);
            __builtin_amdgcn_s_setprio(1);
#pragma unroll
            for (int m = 0; m < 4; ++m)
#pragma unroll
                for (int n = 0; n < 4; ++n)
                    acc[m + 4][n] = __builtin_amdgcn_mfma_f32_16x16x32_bf16(
                        a[m], b[n], acc[m + 4][n], 0, 0, 0);
            __builtin_amdgcn_s_setprio(0);
            // next tile's top wait+barrier provides the trailing sync
        }
    }

    // ---- epilogue: out = acc * alpha[row] * gamma / 127 ----
    float gam = gamma[0];
    int orow0 = tm * 256 + wr * 128 + kgrp * 4;
    int ocol = tn * 256 + wc * 64 + lrow;
#pragma unroll
    for (int mf = 0; mf < 8; ++mf)
#pragma unroll
        for (int r = 0; r < 4; ++r) {
            int row = orow0 + mf * 16 + r;
            float s = alpha[row] * gam / QBF;
            size_t rb = (size_t)row * N_DIM + ocol;
#pragma unroll
            for (int nf = 0; nf < 4; ++nf)
                out[rb + nf * 16] = acc[mf][nf][r] * s;
        }
}

extern "C" void kernel_launch(void* const* d_in, const int* in_sizes, int n_in,
                              void* d_out, int out_size, void* d_ws, size_t ws_size,
                              hipStream_t stream) {
    const float* x  = (const float*)d_in[0];   // [4,2048,2048]
    const float* wt = (const float*)d_in[1];   // [8192,2048]
    float* out = (float*)d_out;                // [4,2048,8192] fp32

    char* ws = (char*)d_ws;
    u16*   xq      = (u16*)ws;                          // 33,554,432 B
    u16*   wq      = (u16*)(ws + 33554432);             // 33,554,432 B
    float* alpha   = (float*)(ws + 67108864);           // 32,768 B
    float* partial = (float*)(ws + 67141632);           // 8,192 B
    float* gamma   = (float*)(ws + 67149824);           // 4 B

    k_abs_partial<<<2048, 256, 0, stream>>>(wt, partial);
    k_gamma<<<1, 256, 0, stream>>>(partial, gamma);
    k_quant_w<<<4096, 256, 0, stream>>>(wt, gamma, wq);
    k_quant_x<<<8192, 256, 0, stream>>>(x, xq, alpha);
    k_gemm<<<1024, 512, 0, stream>>>(xq, wq, alpha, gamma, out);
}

// Round 3
// 324.146 us; speedup vs baseline: 1.2552x; 1.0525x over previous
//
#include <hip/hip_runtime.h>
#include <hip/hip_bf16.h>
#include <stdint.h>

typedef unsigned short u16;
typedef __bf16 bf16x8 __attribute__((ext_vector_type(8)));
typedef float f32x4 __attribute__((ext_vector_type(4)));

#define K_DIM 2048
#define M_DIM 8192   // B*S = 4*2048 tokens
#define N_DIM 8192   // D_OUT
#define QBF   127.0f
#define EPSF  1e-5f
#define NT    64     // K_DIM / 32 sub-tiles

// RNE float->bf16 (exact for our small integers)
__device__ __forceinline__ u16 f2bf(float f) {
    union { float f; unsigned u; } v; v.f = f;
    unsigned r = v.u + 0x7FFFu + ((v.u >> 16) & 1u);
    return (u16)(r >> 16);
}

__device__ __forceinline__ void load_lds16(const void* gsrc, void* ldst) {
    __builtin_amdgcn_global_load_lds(
        (__attribute__((address_space(1))) void*)gsrc,
        (__attribute__((address_space(3))) void*)ldst,
        16, 0, 0);
}

// ---------- Kernel 1: deterministic partial |W| sums ----------
__global__ __launch_bounds__(256) void k_abs_partial(const float* __restrict__ w,
                                                     float* __restrict__ partial) {
    __shared__ float red[256];
    int t = threadIdx.x, b = blockIdx.x;
    const float4* w4 = (const float4*)w;
    size_t base = (size_t)b * 2048;
    float s = 0.f;
#pragma unroll
    for (int j = 0; j < 8; ++j) {
        float4 v = w4[base + j * 256 + t];
        s += fabsf(v.x) + fabsf(v.y) + fabsf(v.z) + fabsf(v.w);
    }
    red[t] = s; __syncthreads();
    for (int off = 128; off > 0; off >>= 1) {
        if (t < off) red[t] += red[t + off];
        __syncthreads();
    }
    if (t == 0) partial[b] = red[0];
}

// ---------- Kernel 2: gamma = sum(partial)/count ----------
__global__ __launch_bounds__(256) void k_gamma(const float* __restrict__ partial,
                                               float* __restrict__ gamma) {
    __shared__ float red[256];
    int t = threadIdx.x;
    float s = 0.f;
#pragma unroll
    for (int j = 0; j < 8; ++j) s += partial[t + j * 256];
    red[t] = s; __syncthreads();
    for (int off = 128; off > 0; off >>= 1) {
        if (t < off) red[t] += red[t + off];
        __syncthreads();
    }
    if (t == 0) gamma[0] = red[0] / 16777216.0f;
}

// ---------- Kernel 3: ternary-quantize W -> bf16 ----------
__global__ __launch_bounds__(256) void k_quant_w(const float* __restrict__ w,
                                                 const float* __restrict__ gamma,
                                                 u16* __restrict__ wq) {
    float g = fmaxf(gamma[0], EPSF);
    int tid = blockIdx.x * 256 + threadIdx.x;
    const float4* w4 = (const float4*)w;
    ushort4* q4 = (ushort4*)wq;
#pragma unroll
    for (int i = 0; i < 4; ++i) {
        int idx = tid + i * 1048576;
        float4 v = w4[idx];
        ushort4 o;
        o.x = f2bf(fminf(fmaxf(rintf(v.x / g), -1.f), 1.f));
        o.y = f2bf(fminf(fmaxf(rintf(v.y / g), -1.f), 1.f));
        o.z = f2bf(fminf(fmaxf(rintf(v.z / g), -1.f), 1.f));
        o.w = f2bf(fminf(fmaxf(rintf(v.w / g), -1.f), 1.f));
        q4[idx] = o;
    }
}

// ---------- Kernel 4: per-token absmax-quantize x -> bf16 ints, alpha ----------
__global__ __launch_bounds__(256) void k_quant_x(const float* __restrict__ x,
                                                 u16* __restrict__ xq,
                                                 float* __restrict__ alpha) {
    __shared__ float red[256];
    int t = threadIdx.x, row = blockIdx.x;
    const float4* x4 = (const float4*)x + (size_t)row * 512;
    float4 v0 = x4[t], v1 = x4[t + 256];
    float m = fmaxf(fmaxf(fabsf(v0.x), fabsf(v0.y)), fmaxf(fabsf(v0.z), fabsf(v0.w)));
    m = fmaxf(m, fmaxf(fmaxf(fabsf(v1.x), fabsf(v1.y)), fmaxf(fabsf(v1.z), fabsf(v1.w))));
    red[t] = m; __syncthreads();
    for (int off = 128; off > 0; off >>= 1) {
        if (t < off) red[t] = fmaxf(red[t], red[t + off]);
        __syncthreads();
    }
    float a = red[0];
    if (t == 0) alpha[row] = a;
    float den = fmaxf(a, EPSF);
    ushort4* q4 = (ushort4*)xq + (size_t)row * 512;
    ushort4 o0, o1;
    o0.x = f2bf(fminf(fmaxf(rintf(v0.x * QBF / den), -QBF), QBF));
    o0.y = f2bf(fminf(fmaxf(rintf(v0.y * QBF / den), -QBF), QBF));
    o0.z = f2bf(fminf(fmaxf(rintf(v0.z * QBF / den), -QBF), QBF));
    o0.w = f2bf(fminf(fmaxf(rintf(v0.w * QBF / den), -QBF), QBF));
    o1.x = f2bf(fminf(fmaxf(rintf(v1.x * QBF / den), -QBF), QBF));
    o1.y = f2bf(fminf(fmaxf(rintf(v1.y * QBF / den), -QBF), QBF));
    o1.z = f2bf(fminf(fmaxf(rintf(v1.z * QBF / den), -QBF), QBF));
    o1.w = f2bf(fminf(fmaxf(rintf(v1.w * QBF / den), -QBF), QBF));
    q4[t] = o0; q4[t + 256] = o1;
}

// ---------- Kernel 5: 256x256 deep-pipelined bf16 MFMA GEMM ----------
// A = xq [M,K], B = wq [N,K] row-major. 512 threads = 8 waves (2x4), wave owns 128x64.
// BK=32 sub-tiles, 4-deep LDS ring (4 x 32KB). Per sub-tile: A 256x32 bf16 (16KB,
// 64B rows of 4 x 16B chunks) then B same at +16KB.
// Bank map: row r chunk c -> banks 16*(r&1) + 4c. XOR source must be bits ABOVE the
// parity bit: phys_chunk = log_chunk ^ ((r>>1)&3). (r&3 collapsed even rows onto 2
// positions -> 4-way conflict, 2.5e7 counted in round 2. (r>>1)&3 gives 2-way = free.)
// Prefetch 3 sub-tiles ahead -> per-tile wait is vmcnt(8), never 0 (T4).
// Per-wave vmcnt ledger: 4 global_load_lds per tile; at tile top outstanding = 12
// (tiles kt..kt+2), need oldest 4 -> vmcnt(8); tail: NT-2 -> 4, NT-1 -> 0.
__global__ __launch_bounds__(512, 2) void k_gemm(const u16* __restrict__ xq,
                                                 const u16* __restrict__ wq,
                                                 const float* __restrict__ alpha,
                                                 const float* __restrict__ gamma,
                                                 float* __restrict__ out) {
    __shared__ __align__(16) char smem[131072];  // 4 ring buffers x 32KB

    int bid = blockIdx.x;
    int wg = (bid & 7) * 128 + (bid >> 3);       // XCD-bijective (1024 % 8 == 0)
    int tm = wg >> 5, tn = wg & 31;

    int t = threadIdx.x;
    int w = t >> 6, l = t & 63;
    int wr = w >> 2, wc = w & 3;                 // 2x4 waves

    // ---- staging descriptors: 4 regions/wave/tile, 1KB each (waves 0-3: A, 4-7: B)
    const u16* srcb[4];
    int dstq[4];
    {
        int rsub = l >> 2;                       // row within 16-row region
        int clog = (l & 3) ^ ((rsub >> 1) & 3);  // pre-swizzled source chunk
#pragma unroll
        for (int j = 0; j < 4; ++j) {
            int q = w * 4 + j;                   // region 0..31
            int isB = q >> 4;
            int r = (q & 15) * 16 + rsub;        // tile-local row 0..255
            int grow = (isB ? tn : tm) * 256 + r;
            srcb[j] = (isB ? wq : xq) + (size_t)grow * K_DIM + clog * 8;
            dstq[j] = q * 1024;                  // wave-uniform LDS offset
        }
    }

    f32x4 acc[8][4];
#pragma unroll
    for (int m = 0; m < 8; ++m)
#pragma unroll
        for (int n = 0; n < 4; ++n) acc[m][n] = (f32x4){0.f, 0.f, 0.f, 0.f};

    int lrow = l & 15, kgrp = l >> 4;
    int cph = (kgrp ^ ((lrow >> 1) & 3)) * 16;   // swizzled read chunk
    int aoff = (wr * 128 + lrow) * 64 + cph;     // + mf*1024
    int boff = 16384 + (wc * 64 + lrow) * 64 + cph;  // + nf*1024

    // ---- prologue: stage sub-tiles 0..2 (12 issues/wave outstanding)
#pragma unroll
    for (int p = 0; p < 3; ++p)
#pragma unroll
        for (int j = 0; j < 4; ++j)
            load_lds16(srcb[j] + (size_t)p * 32, smem + p * 32768 + dstq[j]);

    for (int kt = 0; kt < NT; ++kt) {
        char* sb = smem + (kt & 3) * 32768;
        // tile-boundary wait: retire sub-tile kt's 4 loads, keep the rest in flight
        if (kt < NT - 2)       asm volatile("s_waitcnt vmcnt(8)" ::: "memory");
        else if (kt == NT - 2) asm volatile("s_waitcnt vmcnt(4)" ::: "memory");
        else                   asm volatile("s_waitcnt vmcnt(0)" ::: "memory");
        __builtin_amdgcn_s_barrier();

        bf16x8 b[4];
        {   // ---- phase 0: mf 0-3 ----
            bf16x8 a[4];
#pragma unroll
            for (int i = 0; i < 4; ++i) {
                a[i] = *(const bf16x8*)(sb + aoff + i * 1024);
                b[i] = *(const bf16x8*)(sb + boff + i * 1024);
            }
            if (kt + 3 < NT) {
                char* db = smem + ((kt + 3) & 3) * 32768;
                load_lds16(srcb[0] + (size_t)(kt + 3) * 32, db + dstq[0]);
                load_lds16(srcb[1] + (size_t)(kt + 3) * 32, db + dstq[1]);
            }
            __builtin_amdgcn_s_barrier();
            asm volatile("s_waitcnt lgkmcnt(0)" ::: "memory");
            __builtin_amdgcn_sched_barrier(0);
            __builtin_amdgcn_s_setprio(1);
#pragma unroll
            for (int m = 0; m < 4; ++m)
#pragma unroll
                for (int n = 0; n < 4; ++n)
                    acc[m][n] = __builtin_amdgcn_mfma_f32_16x16x32_bf16(
                        a[m], b[n], acc[m][n], 0, 0, 0);
            __builtin_amdgcn_s_setprio(0);
            __builtin_amdgcn_s_barrier();
        }
        {   // ---- phase 1: mf 4-7 (reuse b) ----
            bf16x8 a[4];
#pragma unroll
            for (int i = 0; i < 4; ++i)
                a[i] = *(const bf16x8*)(sb + aoff + (i + 4) * 1024);
            if (kt + 3 < NT) {
                char* db = smem + ((kt + 3) & 3) * 32768;
                load_lds16(srcb[2] + (size_t)(kt + 3) * 32, db + dstq[2]);
                load_lds16(srcb[3] + (size_t)(kt + 3) * 32, db + dstq[3]);
            }
            __builtin_amdgcn_s_barrier();
            asm volatile("s_waitcnt lgkmcnt(0)" ::: "memory");
            __builtin_amdgcn_sched_barrier(0);
            __builtin_amdgcn_s_setprio(1);
#pragma unroll
            for (int m = 0; m < 4; ++m)
#pragma unroll
                for (int n = 0; n < 4; ++n)
                    acc[m + 4][n] = __builtin_amdgcn_mfma_f32_16x16x32_bf16(
                        a[m], b[n], acc[m + 4][n], 0, 0, 0);
            __builtin_amdgcn_s_setprio(0);
            // next tile's top wait+barrier provides the trailing sync
        }
    }

    // ---- epilogue: out = acc * alpha[row] * gamma / 127 ----
    float gam = gamma[0];
    int orow0 = tm * 256 + wr * 128 + kgrp * 4;
    int ocol = tn * 256 + wc * 64 + lrow;
#pragma unroll
    for (int mf = 0; mf < 8; ++mf)
#pragma unroll
        for (int r = 0; r < 4; ++r) {
            int row = orow0 + mf * 16 + r;
            float s = alpha[row] * gam / QBF;
            size_t rb = (size_t)row * N_DIM + ocol;
#pragma unroll
            for (int nf = 0; nf < 4; ++nf)
                out[rb + nf * 16] = acc[mf][nf][r] * s;
        }
}

extern "C" void kernel_launch(void* const* d_in, const int* in_sizes, int n_in,
                              void* d_out, int out_size, void* d_ws, size_t ws_size,
                              hipStream_t stream) {
    const float* x  = (const float*)d_in[0];   // [4,2048,2048]
    const float* wt = (const float*)d_in[1];   // [8192,2048]
    float* out = (float*)d_out;                // [4,2048,8192] fp32

    char* ws = (char*)d_ws;
    u16*   xq      = (u16*)ws;                          // 33,554,432 B
    u16*   wq      = (u16*)(ws + 33554432);             // 33,554,432 B
    float* alpha   = (float*)(ws + 67108864);           // 32,768 B
    float* partial = (float*)(ws + 67141632);           // 8,192 B
    float* gamma   = (float*)(ws + 67149824);           // 4 B

    k_abs_partial<<<2048, 256, 0, stream>>>(wt, partial);
    k_gamma<<<1, 256, 0, stream>>>(partial, gamma);
    k_quant_w<<<4096, 256, 0, stream>>>(wt, gamma, wq);
    k_quant_x<<<8192, 256, 0, stream>>>(x, xq, alpha);
    k_gemm<<<1024, 512, 0, stream>>>(xq, wq, alpha, gamma, out);
}

// Round 4
// 216.060 us; speedup vs baseline: 1.8831x; 1.5003x over previous
//
#include <hip/hip_runtime.h>
#include <hip/hip_bf16.h>
#include <stdint.h>

typedef unsigned short u16;
typedef int i32x4 __attribute__((ext_vector_type(4)));

#define K_DIM 2048
#define M_DIM 8192   // B*S = 4*2048 tokens
#define N_DIM 8192   // D_OUT
#define QBF   127.0f
#define EPSF  1e-5f
#define NT    32     // K_DIM / 64 sub-tiles (i8: BK=64)

__device__ __forceinline__ void load_lds16(const void* gsrc, void* ldst) {
    __builtin_amdgcn_global_load_lds(
        (__attribute__((address_space(1))) void*)gsrc,
        (__attribute__((address_space(3))) void*)ldst,
        16, 0, 0);
}

// ---------- Kernel 1: deterministic partial |W| sums ----------
__global__ __launch_bounds__(256) void k_abs_partial(const float* __restrict__ w,
                                                     float* __restrict__ partial) {
    __shared__ float red[256];
    int t = threadIdx.x, b = blockIdx.x;
    const float4* w4 = (const float4*)w;
    size_t base = (size_t)b * 2048;
    float s = 0.f;
#pragma unroll
    for (int j = 0; j < 8; ++j) {
        float4 v = w4[base + j * 256 + t];
        s += fabsf(v.x) + fabsf(v.y) + fabsf(v.z) + fabsf(v.w);
    }
    red[t] = s; __syncthreads();
    for (int off = 128; off > 0; off >>= 1) {
        if (t < off) red[t] += red[t + off];
        __syncthreads();
    }
    if (t == 0) partial[b] = red[0];
}

// ---------- Kernel 2: gamma = sum(partial)/count ----------
__global__ __launch_bounds__(256) void k_gamma(const float* __restrict__ partial,
                                               float* __restrict__ gamma) {
    __shared__ float red[256];
    int t = threadIdx.x;
    float s = 0.f;
#pragma unroll
    for (int j = 0; j < 8; ++j) s += partial[t + j * 256];
    red[t] = s; __syncthreads();
    for (int off = 128; off > 0; off >>= 1) {
        if (t < off) red[t] += red[t + off];
        __syncthreads();
    }
    if (t == 0) gamma[0] = red[0] / 16777216.0f;
}

// ---------- Kernel 3: ternary-quantize W -> int8 ----------
__global__ __launch_bounds__(256) void k_quant_w(const float* __restrict__ w,
                                                 const float* __restrict__ gamma,
                                                 uint* __restrict__ wq) {
    float g = fmaxf(gamma[0], EPSF);
    int tid = blockIdx.x * 256 + threadIdx.x;    // 4,194,304 threads
    float4 v = ((const float4*)w)[tid];
    int a = (int)fminf(fmaxf(rintf(v.x / g), -1.f), 1.f);
    int b = (int)fminf(fmaxf(rintf(v.y / g), -1.f), 1.f);
    int c = (int)fminf(fmaxf(rintf(v.z / g), -1.f), 1.f);
    int d = (int)fminf(fmaxf(rintf(v.w / g), -1.f), 1.f);
    wq[tid] = (a & 255) | ((b & 255) << 8) | ((c & 255) << 16) | ((d & 255) << 24);
}

// ---------- Kernel 4: per-token absmax-quantize x -> int8, alpha ----------
__global__ __launch_bounds__(256) void k_quant_x(const float* __restrict__ x,
                                                 uint* __restrict__ xq,
                                                 float* __restrict__ alpha) {
    __shared__ float red[256];
    int t = threadIdx.x, row = blockIdx.x;
    const float4* x4 = (const float4*)x + (size_t)row * 512;
    float4 v0 = x4[t], v1 = x4[t + 256];
    float m = fmaxf(fmaxf(fabsf(v0.x), fabsf(v0.y)), fmaxf(fabsf(v0.z), fabsf(v0.w)));
    m = fmaxf(m, fmaxf(fmaxf(fabsf(v1.x), fabsf(v1.y)), fmaxf(fabsf(v1.z), fabsf(v1.w))));
    red[t] = m; __syncthreads();
    for (int off = 128; off > 0; off >>= 1) {
        if (t < off) red[t] = fmaxf(red[t], red[t + off]);
        __syncthreads();
    }
    float a = red[0];
    if (t == 0) alpha[row] = a;
    float den = fmaxf(a, EPSF);
    uint* q = xq + (size_t)row * 512;
    int q0 = (int)fminf(fmaxf(rintf(v0.x * QBF / den), -QBF), QBF);
    int q1 = (int)fminf(fmaxf(rintf(v0.y * QBF / den), -QBF), QBF);
    int q2 = (int)fminf(fmaxf(rintf(v0.z * QBF / den), -QBF), QBF);
    int q3 = (int)fminf(fmaxf(rintf(v0.w * QBF / den), -QBF), QBF);
    q[t] = (q0 & 255) | ((q1 & 255) << 8) | ((q2 & 255) << 16) | ((q3 & 255) << 24);
    q0 = (int)fminf(fmaxf(rintf(v1.x * QBF / den), -QBF), QBF);
    q1 = (int)fminf(fmaxf(rintf(v1.y * QBF / den), -QBF), QBF);
    q2 = (int)fminf(fmaxf(rintf(v1.z * QBF / den), -QBF), QBF);
    q3 = (int)fminf(fmaxf(rintf(v1.w * QBF / den), -QBF), QBF);
    q[t + 256] = (q0 & 255) | ((q1 & 255) << 8) | ((q2 & 255) << 16) | ((q3 & 255) << 24);
}

// ---------- Kernel 5: 256x256 deep-pipelined i8 MFMA GEMM ----------
// A = xq [M,K] int8, B = wq [N,K] int8. 512 threads = 8 waves (2x4), wave owns 128x64.
// mfma_i32_16x16x64_i8: lane l holds row l&15, k-bytes (l>>4)*16..+16 — same 16B/lane
// geometry as the verified bf16 16x16x32 path. i32 accumulation is exact.
// BK=64 sub-tiles (64B rows = 4 x 16B chunks), 4-deep LDS ring (4 x 32KB).
// Swizzle: phys_chunk = log_chunk ^ ((row>>1)&3) — measured 0 conflicts (round 3).
// One barrier per subtile: vmcnt(N) + s_barrier at top. Safe because every wave
// drains lgkmcnt(0) (all reads of slot kt-1 done) before reaching the next top
// barrier, and staging for kt+3 (same slot as kt-1) is issued only after it.
// vmcnt ledger (4 issues/wave/subtile, prefetch depth 3): top of kt -> 12 in
// flight, retire oldest 4 -> vmcnt(8); kt==NT-2 -> 4; kt==NT-1 -> 0.
// Counted lgkmcnt(4): burst-1's 4 A-frag reads overlap burst-0's 16 MFMA (T4).
__global__ __launch_bounds__(512, 2) void k_gemm(const uint8_t* __restrict__ xq,
                                                 const uint8_t* __restrict__ wq,
                                                 const float* __restrict__ alpha,
                                                 const float* __restrict__ gamma,
                                                 float* __restrict__ out) {
    __shared__ __align__(16) char smem[131072];  // 4 ring buffers x 32KB

    int bid = blockIdx.x;
    int wg = (bid & 7) * 128 + (bid >> 3);       // XCD-bijective (1024 % 8 == 0)
    int tm = wg >> 5, tn = wg & 31;

    int t = threadIdx.x;
    int w = t >> 6, l = t & 63;
    int wr = w >> 2, wc = w & 3;                 // 2x4 waves

    // ---- staging descriptors: 4 regions/wave/subtile, 1KB each (waves 0-3: A, 4-7: B)
    const uint8_t* srcb[4];
    int dstq[4];
    {
        int rsub = l >> 2;                       // row within 16-row region
        int clog = (l & 3) ^ ((rsub >> 1) & 3);  // pre-swizzled source chunk
#pragma unroll
        for (int j = 0; j < 4; ++j) {
            int q = w * 4 + j;                   // region 0..31
            int isB = q >> 4;
            int r = (q & 15) * 16 + rsub;        // tile-local row 0..255
            int grow = (isB ? tn : tm) * 256 + r;
            srcb[j] = (isB ? wq : xq) + (size_t)grow * K_DIM + clog * 16;
            dstq[j] = q * 1024;                  // wave-uniform LDS offset
        }
    }

    i32x4 acc[8][4];
#pragma unroll
    for (int m = 0; m < 8; ++m)
#pragma unroll
        for (int n = 0; n < 4; ++n) acc[m][n] = (i32x4){0, 0, 0, 0};

    int lrow = l & 15, kgrp = l >> 4;
    int cph = (kgrp ^ ((lrow >> 1) & 3)) * 16;   // swizzled read chunk
    int aoff = (wr * 128 + lrow) * 64 + cph;     // + mf*1024
    int boff = 16384 + (wc * 64 + lrow) * 64 + cph;  // + nf*1024

    // ---- prologue: stage sub-tiles 0..2 (12 issues/wave outstanding)
#pragma unroll
    for (int p = 0; p < 3; ++p)
#pragma unroll
        for (int j = 0; j < 4; ++j)
            load_lds16(srcb[j] + (size_t)p * 64, smem + p * 32768 + dstq[j]);

    for (int kt = 0; kt < NT; ++kt) {
        char* sb = smem + (kt & 3) * 32768;
        if (kt < NT - 2)       asm volatile("s_waitcnt vmcnt(8)" ::: "memory");
        else if (kt == NT - 2) asm volatile("s_waitcnt vmcnt(4)" ::: "memory");
        else                   asm volatile("s_waitcnt vmcnt(0)" ::: "memory");
        __builtin_amdgcn_s_barrier();

        i32x4 a[8], b[4];
        // burst-0 operands first (oldest 8 DS ops for the counted wait)
#pragma unroll
        for (int i = 0; i < 4; ++i)
            b[i] = *(const i32x4*)(sb + boff + i * 1024);
#pragma unroll
        for (int i = 0; i < 4; ++i)
            a[i] = *(const i32x4*)(sb + aoff + i * 1024);
        // prefetch staging for kt+3 (slot (kt+3)&3 == (kt-1)&3, freed above)
        if (kt + 3 < NT) {
            char* db = smem + ((kt + 3) & 3) * 32768;
#pragma unroll
            for (int j = 0; j < 4; ++j)
                load_lds16(srcb[j] + (size_t)(kt + 3) * 64, db + dstq[j]);
        }
        // burst-1 A-frags (overlap burst-0 MFMA via lgkmcnt(4))
#pragma unroll
        for (int i = 4; i < 8; ++i)
            a[i] = *(const i32x4*)(sb + aoff + i * 1024);

        asm volatile("s_waitcnt lgkmcnt(4)" ::: "memory");
        __builtin_amdgcn_sched_barrier(0);
        __builtin_amdgcn_s_setprio(1);
#pragma unroll
        for (int m = 0; m < 4; ++m)
#pragma unroll
            for (int n = 0; n < 4; ++n)
                acc[m][n] = __builtin_amdgcn_mfma_i32_16x16x64_i8(
                    a[m], b[n], acc[m][n], 0, 0, 0);
        __builtin_amdgcn_s_setprio(0);

        asm volatile("s_waitcnt lgkmcnt(0)" ::: "memory");
        __builtin_amdgcn_sched_barrier(0);
        __builtin_amdgcn_s_setprio(1);
#pragma unroll
        for (int m = 0; m < 4; ++m)
#pragma unroll
            for (int n = 0; n < 4; ++n)
                acc[m + 4][n] = __builtin_amdgcn_mfma_i32_16x16x64_i8(
                    a[m + 4], b[n], acc[m + 4][n], 0, 0, 0);
        __builtin_amdgcn_s_setprio(0);
    }

    // ---- epilogue: out = (float)acc * alpha[row] * gamma / 127 ----
    float gam = gamma[0];
    int orow0 = tm * 256 + wr * 128 + kgrp * 4;
    int ocol = tn * 256 + wc * 64 + lrow;
#pragma unroll
    for (int mf = 0; mf < 8; ++mf)
#pragma unroll
        for (int r = 0; r < 4; ++r) {
            int row = orow0 + mf * 16 + r;
            float s = alpha[row] * gam / QBF;
            size_t rb = (size_t)row * N_DIM + ocol;
#pragma unroll
            for (int nf = 0; nf < 4; ++nf)
                out[rb + nf * 16] = (float)acc[mf][nf][r] * s;
        }
}

extern "C" void kernel_launch(void* const* d_in, const int* in_sizes, int n_in,
                              void* d_out, int out_size, void* d_ws, size_t ws_size,
                              hipStream_t stream) {
    const float* x  = (const float*)d_in[0];   // [4,2048,2048]
    const float* wt = (const float*)d_in[1];   // [8192,2048]
    float* out = (float*)d_out;                // [4,2048,8192] fp32

    char* ws = (char*)d_ws;
    uint8_t* xq     = (uint8_t*)ws;                     // 16,777,216 B
    uint8_t* wq     = (uint8_t*)(ws + 16777216);        // 16,777,216 B
    float* alpha    = (float*)(ws + 33554432);          // 32,768 B
    float* partial  = (float*)(ws + 33587200);          // 8,192 B
    float* gamma    = (float*)(ws + 33595392);          // 4 B

    k_abs_partial<<<2048, 256, 0, stream>>>(wt, partial);
    k_gamma<<<1, 256, 0, stream>>>(partial, gamma);
    k_quant_w<<<16384, 256, 0, stream>>>(wt, gamma, (uint*)wq);
    k_quant_x<<<8192, 256, 0, stream>>>(x, (uint*)xq, alpha);
    k_gemm<<<1024, 512, 0, stream>>>(xq, wq, alpha, gamma, out);
}